// Round 5
// baseline (4105.105 us; speedup 1.0000x reference)
//
#include <hip/hip_runtime.h>
#include <hip/hip_bf16.h>

#define TLEN 512
#define BATCH 64
#define ISZ 256
#define HSZ 512
#define OSZ 256
#define G4 2048

typedef float f32x4 __attribute__((ext_vector_type(4)));
typedef short short8 __attribute__((ext_vector_type(8)));
typedef int int4v __attribute__((ext_vector_type(4)));

#define MFMA(a, b, c) __builtin_amdgcn_mfma_f32_16x16x32_bf16((a), (b), (c), 0, 0, 0)

__device__ __forceinline__ unsigned short f2bf(float x) {
    unsigned int u = __float_as_uint(x);
    u = (u + 0x7fffu + ((u >> 16) & 1u)) >> 16;
    return (unsigned short)u;
}
__device__ __forceinline__ float bf2f(unsigned short h) {
    return __uint_as_float(((unsigned int)h) << 16);
}
__device__ __forceinline__ float sigmoidf_(float x) { return 1.0f / (1.0f + __expf(-x)); }
__device__ __forceinline__ float tanhf_(float x) { return 1.0f - 2.0f / (__expf(2.0f * x) + 1.0f); }

// ---------------- Phase A: x_gates = inputs @ W_ih^T + (b_ih + b_hh), bf16 out ---------------
__global__ void __launch_bounds__(512, 1) xg_gemm(
    const float* __restrict__ inp, const float* __restrict__ Wih,
    const float* __restrict__ b_ih, const float* __restrict__ b_hh,
    unsigned short* __restrict__ xg)
{
    __shared__ short8 blds[8][8][64];   // [ntile][kf][lane], 64 KB
    const int tid = threadIdx.x;
    {
        int row = tid >> 2;             // 0..127 within N-tile block
        int kseg = (tid & 3) * 64;
        int nt = row >> 4, nn = row & 15;
        const float* src = Wih + (size_t)(blockIdx.y * 128 + row) * ISZ + kseg;
        for (int kk = 0; kk < 64; ++kk) {
            int k = kseg + kk;
            int kf = k >> 5, sub = k & 31;
            ((unsigned short*)&blds[nt][kf][((sub >> 3) << 4) | nn])[sub & 7] = f2bf(src[kk]);
        }
    }
    __syncthreads();
    const int wave = tid >> 6, lane = tid & 63;
    const int m0 = blockIdx.x * 128 + wave * 16;
    f32x4 acc[8];
    #pragma unroll
    for (int i = 0; i < 8; ++i) acc[i] = (f32x4){0.f, 0.f, 0.f, 0.f};
    const float* arow = inp + (size_t)(m0 + (lane & 15)) * ISZ + ((lane >> 4) * 8);
    #pragma unroll
    for (int kf = 0; kf < 8; ++kf) {
        f32x4 a0 = *(const f32x4*)(arow + kf * 32);
        f32x4 a1 = *(const f32x4*)(arow + kf * 32 + 4);
        short8 af;
        #pragma unroll
        for (int i = 0; i < 4; ++i) { af[i] = (short)f2bf(a0[i]); af[4 + i] = (short)f2bf(a1[i]); }
        #pragma unroll
        for (int nt = 0; nt < 8; ++nt)
            acc[nt] = MFMA(af, blds[nt][kf][lane], acc[nt]);
    }
    const int nn = lane & 15;
    #pragma unroll
    for (int nt = 0; nt < 8; ++nt) {
        int nc = blockIdx.y * 128 + nt * 16 + nn;
        float bias = b_ih[nc] + b_hh[nc];
        #pragma unroll
        for (int r = 0; r < 4; ++r) {
            int m = m0 + (lane >> 4) * 4 + r;
            xg[(size_t)m * G4 + nc] = f2bf(acc[nt][r] + bias);
        }
    }
}

// ---------------- Phase B: persistent scan, 32 WGs x 256, tagged-word LLC exchange ----------
// h exchange: self-validating u32 words  (bf16(h) << 16) | step_tag  in
// hbuf[parity][64 rows][512 cols]. Producer: 4 plain agent-scope stores, NO ack, NO flag.
// Consumer: load all 32 dwordx4 (sc0 sc1), vmcnt(0), check the 128 embedded tags, retry
// until all fresh. Double parity buffer + monotone tags => no overwrite-before-read:
// a WG entering step t+1 implies all WGs published h_t, which implies all WGs finished
// reading h_{t-1} (the buffer being overwritten).
__global__ void __attribute__((amdgpu_waves_per_eu(1, 1))) __launch_bounds__(256, 1) lstm_scan(
    const float* __restrict__ Whh, const unsigned short* __restrict__ xg,
    unsigned short* __restrict__ hs, unsigned int* __restrict__ hbuf,
    float* __restrict__ out_tail)
{
    __shared__ short8 wlds[4][16][64];   // [gate][kf][lane], 64 KB
    const int wg = blockIdx.x, tid = threadIdx.x;
    const int wave = tid >> 6, lane = tid & 63;
    const int l15 = lane & 15, l4 = lane >> 4;
    const int col = wg * 16 + l15;

    // wave g loads gate g's B-fragments: lane holds Whh[g*512 + wg*16 + l15][kf*32 + l4*8 + e]
    {
        const int g = wave;
        const float* wrow = Whh + (size_t)(g * HSZ + wg * 16 + l15) * HSZ + l4 * 8;
        #pragma unroll
        for (int kf = 0; kf < 16; ++kf) {
            f32x4 w0 = *(const f32x4*)(wrow + kf * 32);
            f32x4 w1 = *(const f32x4*)(wrow + kf * 32 + 4);
            short8 f;
            #pragma unroll
            for (int e = 0; e < 4; ++e) { f[e] = (short)f2bf(w0[e]); f[4 + e] = (short)f2bf(w1[e]); }
            wlds[g][kf][lane] = f;
        }
    }
    __syncthreads();

    float cr[4] = {0.f, 0.f, 0.f, 0.f};
    const int mbase = wave * 16 + l4 * 4;

    #pragma unroll 1
    for (int t = 0; t < TLEN; ++t) {
        // ---- xg loads: issued first, overlapped with the poll/validate round ----
        unsigned int xgv[4][4];
        {
            const char* x0 = (const char*)(xg + (size_t)(t * BATCH + mbase) * G4 + col);
            #pragma unroll
            for (int r = 0; r < 4; ++r) {
                const char* xr = x0 + r * (G4 * 2);
                asm volatile("global_load_ushort %0, %1, off offset:0"    : "=v"(xgv[0][r]) : "v"(xr));
                asm volatile("global_load_ushort %0, %1, off offset:1024" : "=v"(xgv[1][r]) : "v"(xr));
                asm volatile("global_load_ushort %0, %1, off offset:2048" : "=v"(xgv[2][r]) : "v"(xr));
                asm volatile("global_load_ushort %0, %1, off offset:3072" : "=v"(xgv[3][r]) : "v"(xr));
            }
        }

        f32x4 acc[4];
        #pragma unroll
        for (int g = 0; g < 4; ++g) acc[g] = (f32x4){0.f, 0.f, 0.f, 0.f};

        if (t > 0) {
            const unsigned tag = (unsigned)t;
            // row = wave*16 + l15; this lane's slice starts at col l4*8, 128 B per kf step
            const char* hb = (const char*)hbuf + (t & 1) * 131072
                           + (size_t)(wave * 16 + l15) * 2048 + l4 * 32;
            int4v hv[32];
            while (true) {
                #pragma unroll
                for (int kf = 0; kf < 16; ++kf) {
                    asm volatile("global_load_dwordx4 %0, %1, off offset:%2 sc0 sc1"
                                 : "=&v"(hv[2 * kf])     : "v"(hb), "i"(kf * 128));
                    asm volatile("global_load_dwordx4 %0, %1, off offset:%2 sc0 sc1"
                                 : "=&v"(hv[2 * kf + 1]) : "v"(hb), "i"(kf * 128 + 16));
                }
                asm volatile("s_waitcnt vmcnt(0)" ::: "memory");
                __builtin_amdgcn_sched_barrier(0);
                unsigned bad = 0;
                #pragma unroll
                for (int w = 0; w < 32; ++w) {
                    bad |= (unsigned)(hv[w][0] ^ (int)tag);
                    bad |= (unsigned)(hv[w][1] ^ (int)tag);
                    bad |= (unsigned)(hv[w][2] ^ (int)tag);
                    bad |= (unsigned)(hv[w][3] ^ (int)tag);
                }
                if (__all((bad & 0xFFFFu) == 0)) break;
            }
            __builtin_amdgcn_sched_barrier(0);
            #pragma unroll
            for (int kf = 0; kf < 16; ++kf) {
                int4v w0 = hv[2 * kf], w1 = hv[2 * kf + 1];
                int4v f;
                f[0] = (int)(((unsigned)w0[0] >> 16) | ((unsigned)w0[1] & 0xFFFF0000u));
                f[1] = (int)(((unsigned)w0[2] >> 16) | ((unsigned)w0[3] & 0xFFFF0000u));
                f[2] = (int)(((unsigned)w1[0] >> 16) | ((unsigned)w1[1] & 0xFFFF0000u));
                f[3] = (int)(((unsigned)w1[2] >> 16) | ((unsigned)w1[3] & 0xFFFF0000u));
                short8 a = *(short8*)&f;
                acc[0] = MFMA(a, wlds[0][kf][lane], acc[0]);
                acc[1] = MFMA(a, wlds[1][kf][lane], acc[1]);
                acc[2] = MFMA(a, wlds[2][kf][lane], acc[2]);
                acc[3] = MFMA(a, wlds[3][kf][lane], acc[3]);
            }
        }
        asm volatile("s_waitcnt vmcnt(0)" ::: "memory");   // covers xg loads (t==0 path too)
        __builtin_amdgcn_sched_barrier(0);

        // ---- gate math (fp32), c in registers ----
        float hnv[4];
        #pragma unroll
        for (int r = 0; r < 4; ++r) {
            float iv = acc[0][r] + bf2f((unsigned short)xgv[0][r]);
            float fv2= acc[1][r] + bf2f((unsigned short)xgv[1][r]);
            float gv = acc[2][r] + bf2f((unsigned short)xgv[2][r]);
            float ov = acc[3][r] + bf2f((unsigned short)xgv[3][r]);
            float si = sigmoidf_(iv), sf = sigmoidf_(fv2), so = sigmoidf_(ov);
            float tg = tanhf_(gv);
            float cn = sf * cr[r] + si * tg;
            cr[r] = cn;
            hnv[r] = so * tanhf_(cn);
        }

        // ---- publish tagged h_{t+1}: 4 agent-scope stores, no ack, no flag ----
        {
            const unsigned ptag = (unsigned)(t + 1);
            const unsigned pbase = ((unsigned)((t + 1) & 1)) * 32768u + (unsigned)col;
            #pragma unroll
            for (int r = 0; r < 4; ++r) {
                unsigned word = (((unsigned)f2bf(hnv[r])) << 16) | ptag;
                __hip_atomic_store(&hbuf[pbase + (unsigned)(mbase + r) * 512], word,
                                   __ATOMIC_RELAXED, __HIP_MEMORY_SCOPE_AGENT);
            }
        }

        // ---- off-critical-path stores: hs history (+ tails at t==511), plain cached ----
        #pragma unroll
        for (int r = 0; r < 4; ++r) {
            int m = mbase + r;
            hs[((size_t)t * BATCH + m) * HSZ + col] = f2bf(hnv[r]);
            if (t == TLEN - 1) {
                out_tail[(size_t)m * HSZ + col] = hnv[r];                      // h_T
                out_tail[(size_t)BATCH * HSZ + (size_t)m * HSZ + col] = cr[r]; // c_T
            }
        }
    }
}

// ---------------- Phase C: outputs = hs @ W_out^T + b_out (fp32 out) ------------------------
__global__ void __launch_bounds__(512, 1) out_gemm(
    const unsigned short* __restrict__ hs, const float* __restrict__ Wout,
    const float* __restrict__ b_out, float* __restrict__ out)
{
    __shared__ short8 blds[4][16][64];  // 64 KB
    const int tid = threadIdx.x;
    {
        int row = tid >> 3;             // 0..63
        int kseg = (tid & 7) * 64;
        int nt = row >> 4, nn = row & 15;
        const float* src = Wout + (size_t)(blockIdx.y * 64 + row) * HSZ + kseg;
        for (int kk = 0; kk < 64; ++kk) {
            int k = kseg + kk;
            int kf = k >> 5, sub = k & 31;
            ((unsigned short*)&blds[nt][kf][((sub >> 3) << 4) | nn])[sub & 7] = f2bf(src[kk]);
        }
    }
    __syncthreads();
    const int wave = tid >> 6, lane = tid & 63;
    const int m0 = blockIdx.x * 128 + wave * 16;
    f32x4 acc[4];
    #pragma unroll
    for (int i = 0; i < 4; ++i) acc[i] = (f32x4){0.f, 0.f, 0.f, 0.f};
    const unsigned short* arow = hs + (size_t)(m0 + (lane & 15)) * HSZ + ((lane >> 4) * 8);
    #pragma unroll
    for (int kf = 0; kf < 16; ++kf) {
        short8 a = *(const short8*)(arow + kf * 32);
        #pragma unroll
        for (int nt = 0; nt < 4; ++nt)
            acc[nt] = MFMA(a, blds[nt][kf][lane], acc[nt]);
    }
    const int nn = lane & 15;
    #pragma unroll
    for (int nt = 0; nt < 4; ++nt) {
        int nc = blockIdx.y * 64 + nt * 16 + nn;
        float bias = b_out[nc];
        #pragma unroll
        for (int r = 0; r < 4; ++r) {
            int m = m0 + (lane >> 4) * 4 + r;
            out[(size_t)m * OSZ + nc] = acc[nt][r] + bias;
        }
    }
}

extern "C" void kernel_launch(void* const* d_in, const int* in_sizes, int n_in,
                              void* d_out, int out_size, void* d_ws, size_t ws_size,
                              hipStream_t stream)
{
    const float* inputs = (const float*)d_in[0];  // [512,64,256]
    const float* W_ih  = (const float*)d_in[1];   // [2048,256]
    const float* W_hh  = (const float*)d_in[2];   // [2048,512]
    const float* b_ih  = (const float*)d_in[3];
    const float* b_hh  = (const float*)d_in[4];
    const float* W_out = (const float*)d_in[5];   // [256,512]
    const float* b_out = (const float*)d_in[6];
    float* out = (float*)d_out;

    char* ws = (char*)d_ws;
    unsigned short* xg = (unsigned short*)ws;                              // 134,217,728 B
    unsigned short* hs = (unsigned short*)(ws + 134217728);                //  33,554,432 B
    unsigned int* hbuf = (unsigned int*)(ws + 134217728 + 33554432);       //     262,144 B

    xg_gemm<<<dim3(256, 16), 512, 0, stream>>>(inputs, W_ih, b_ih, b_hh, xg);

    float* out_tail = out + (size_t)TLEN * BATCH * OSZ;
    const float* whh_p = W_hh;
    const unsigned short* xg_p = xg;
    unsigned short* hs_p = hs;
    unsigned int* hbuf_p = hbuf;
    float* tail_p = out_tail;
    void* scan_args[] = { &whh_p, &xg_p, &hs_p, &hbuf_p, &tail_p };
    hipLaunchCooperativeKernel((void*)lstm_scan, dim3(32), dim3(256), scan_args, 0, stream);

    out_gemm<<<dim3(256, 4), 512, 0, stream>>>(hs, W_out, b_out, out);
}

// Round 6
// 3286.280 us; speedup vs baseline: 1.2492x; 1.2492x over previous
//
#include <hip/hip_runtime.h>
#include <hip/hip_bf16.h>

#define TLEN 512
#define BATCH 64
#define ISZ 256
#define HSZ 512
#define OSZ 256
#define G4 2048

typedef float f32x4 __attribute__((ext_vector_type(4)));
typedef short short8 __attribute__((ext_vector_type(8)));
typedef int int2v __attribute__((ext_vector_type(2)));
typedef int int4v __attribute__((ext_vector_type(4)));

#define MFMA(a, b, c) __builtin_amdgcn_mfma_f32_16x16x32_bf16((a), (b), (c), 0, 0, 0)

__device__ __forceinline__ unsigned short f2bf(float x) {
    unsigned int u = __float_as_uint(x);
    u = (u + 0x7fffu + ((u >> 16) & 1u)) >> 16;
    return (unsigned short)u;
}
__device__ __forceinline__ float bf2f(unsigned short h) {
    return __uint_as_float(((unsigned int)h) << 16);
}
__device__ __forceinline__ float sigmoidf_(float x) { return 1.0f / (1.0f + __expf(-x)); }
__device__ __forceinline__ float tanhf_(float x) { return 1.0f - 2.0f / (__expf(2.0f * x) + 1.0f); }

// ---------------- Phase A: x_gates = inputs @ W_ih^T + (b_ih + b_hh) -------------------------
// Output layout: xg[t][col][gate][batch] bf16 — elem ((t*512+col)*4+gate)*64 + b — so the scan
// reads a lane's 4 gates x 4 rows with 4 dwordx2 off one base address.
__global__ void __launch_bounds__(512, 1) xg_gemm(
    const float* __restrict__ inp, const float* __restrict__ Wih,
    const float* __restrict__ b_ih, const float* __restrict__ b_hh,
    unsigned short* __restrict__ xg, int* __restrict__ flags)
{
    __shared__ short8 blds[8][8][64];   // [ntile][kf][lane], 64 KB
    const int tid = threadIdx.x;
    // re-zero the scan's flag cachelines every launch (agent-scope, LLC-visible)
    if (blockIdx.x == 0 && blockIdx.y == 0 && tid < 128)
        __hip_atomic_store(&flags[tid], 0, __ATOMIC_RELAXED, __HIP_MEMORY_SCOPE_AGENT);
    {
        int row = tid >> 2;             // 0..127 within N-tile block
        int kseg = (tid & 3) * 64;
        int nt = row >> 4, nn = row & 15;
        const float* src = Wih + (size_t)(blockIdx.y * 128 + row) * ISZ + kseg;
        for (int kk = 0; kk < 64; ++kk) {
            int k = kseg + kk;
            int kf = k >> 5, sub = k & 31;
            ((unsigned short*)&blds[nt][kf][((sub >> 3) << 4) | nn])[sub & 7] = f2bf(src[kk]);
        }
    }
    __syncthreads();
    const int wave = tid >> 6, lane = tid & 63;
    const int m0 = blockIdx.x * 128 + wave * 16;
    f32x4 acc[8];
    #pragma unroll
    for (int i = 0; i < 8; ++i) acc[i] = (f32x4){0.f, 0.f, 0.f, 0.f};
    const float* arow = inp + (size_t)(m0 + (lane & 15)) * ISZ + ((lane >> 4) * 8);
    #pragma unroll
    for (int kf = 0; kf < 8; ++kf) {
        f32x4 a0 = *(const f32x4*)(arow + kf * 32);
        f32x4 a1 = *(const f32x4*)(arow + kf * 32 + 4);
        short8 af;
        #pragma unroll
        for (int i = 0; i < 4; ++i) { af[i] = (short)f2bf(a0[i]); af[4 + i] = (short)f2bf(a1[i]); }
        #pragma unroll
        for (int nt = 0; nt < 8; ++nt)
            acc[nt] = MFMA(af, blds[nt][kf][lane], acc[nt]);
    }
    const int nn = lane & 15;
    const int mf = m0 + (lane >> 4) * 4;        // flat row of r=0 (4-aligned, within one t)
    const int tt = mf >> 6, bb = mf & 63;
    #pragma unroll
    for (int nt = 0; nt < 8; ++nt) {
        int nc = blockIdx.y * 128 + nt * 16 + nn;
        float bias = b_ih[nc] + b_hh[nc];
        int colc = nc & 511, gate = nc >> 9;
        unsigned lo = (unsigned)f2bf(acc[nt][0] + bias) | ((unsigned)f2bf(acc[nt][1] + bias) << 16);
        unsigned hi = (unsigned)f2bf(acc[nt][2] + bias) | ((unsigned)f2bf(acc[nt][3] + bias) << 16);
        int2v w; w[0] = (int)lo; w[1] = (int)hi;
        *(int2v*)((char*)xg + (size_t)(tt * 512 + colc) * 512 + gate * 128 + bb * 2) = w;
    }
}

// ---------------- Phase B: persistent scan, 32 WGs x 256, flag-pipelined LLC exchange -------
// Per WG: 16 hidden cols (all 4 gates). Per wave: 16 batch rows (a batch-group), produced by
// wave w of every WG and consumed by wave w of every WG — flags are per (wave, wg).
// h: bf16 in hbuf[parity][64 rows][512 cols]; producer: paired-u32 agent stores -> vmcnt(0)
// -> flag; consumer: poll 32 flags (one cacheline) -> 16 dwordx4 in ONE asm block (forces 64
// dst VGPRs => single LLC round trip) -> vmcnt(0) -> MFMA.
__global__ void __attribute__((amdgpu_waves_per_eu(1, 1))) __launch_bounds__(256, 1) lstm_scan(
    const float* __restrict__ Whh, const unsigned short* __restrict__ xg,
    unsigned short* __restrict__ hs, unsigned int* __restrict__ hbuf,
    int* __restrict__ flags, float* __restrict__ out_tail)
{
    __shared__ short8 wlds[4][16][64];   // [gate][kf][lane], 64 KB
    const int wg = blockIdx.x, tid = threadIdx.x;
    const int wave = tid >> 6, lane = tid & 63;
    const int l15 = lane & 15, l4 = lane >> 4;
    const int col = wg * 16 + l15;

    // wave g loads gate g's B-fragments: lane holds Whh[g*512 + wg*16 + l15][kf*32 + l4*8 + e]
    {
        const int g = wave;
        const float* wrow = Whh + (size_t)(g * HSZ + wg * 16 + l15) * HSZ + l4 * 8;
        #pragma unroll
        for (int kf = 0; kf < 16; ++kf) {
            f32x4 w0 = *(const f32x4*)(wrow + kf * 32);
            f32x4 w1 = *(const f32x4*)(wrow + kf * 32 + 4);
            short8 f;
            #pragma unroll
            for (int e = 0; e < 4; ++e) { f[e] = (short)f2bf(w0[e]); f[4 + e] = (short)f2bf(w1[e]); }
            wlds[g][kf][lane] = f;
        }
    }
    __syncthreads();

    float cr[4] = {0.f, 0.f, 0.f, 0.f};
    const int mbase = wave * 16 + l4 * 4;

    #pragma unroll 1
    for (int t = 0; t < TLEN; ++t) {
        // ---- xg loads: 4 dwordx2 off one base, issued before the poll ----
        int2v xv[4];
        {
            const char* xb = (const char*)xg + (size_t)(t * 512 + col) * 512 + mbase * 2;
            asm volatile(
                "global_load_dwordx2 %0, %4, off offset:0\n\t"
                "global_load_dwordx2 %1, %4, off offset:128\n\t"
                "global_load_dwordx2 %2, %4, off offset:256\n\t"
                "global_load_dwordx2 %3, %4, off offset:384"
                : "=&v"(xv[0]), "=&v"(xv[1]), "=&v"(xv[2]), "=&v"(xv[3])
                : "v"(xb) : "memory");
        }

        f32x4 acc[4];
        #pragma unroll
        for (int g = 0; g < 4; ++g) acc[g] = (f32x4){0.f, 0.f, 0.f, 0.f};

        int4v hv[16];
        if (t > 0) {
            // ---- poll 32 producer flags (one 128-B cacheline per batch-group) ----
            const int idx = wave * 32 + (lane & 31);
            int fv;
            do {
                fv = __hip_atomic_load(&flags[idx], __ATOMIC_RELAXED, __HIP_MEMORY_SCOPE_AGENT);
            } while (__all(fv >= t) == 0);
            __builtin_amdgcn_sched_barrier(0);
            // ---- h loads: ONE asm block, 16 dwordx4 outputs live simultaneously ----
            const char* hb = (const char*)hbuf + (t & 1) * 65536
                           + (size_t)(wave * 16 + l15) * 1024 + l4 * 16;
            asm volatile(
                "global_load_dwordx4 %0, %16, off offset:0 sc0 sc1\n\t"
                "global_load_dwordx4 %1, %16, off offset:64 sc0 sc1\n\t"
                "global_load_dwordx4 %2, %16, off offset:128 sc0 sc1\n\t"
                "global_load_dwordx4 %3, %16, off offset:192 sc0 sc1\n\t"
                "global_load_dwordx4 %4, %16, off offset:256 sc0 sc1\n\t"
                "global_load_dwordx4 %5, %16, off offset:320 sc0 sc1\n\t"
                "global_load_dwordx4 %6, %16, off offset:384 sc0 sc1\n\t"
                "global_load_dwordx4 %7, %16, off offset:448 sc0 sc1\n\t"
                "global_load_dwordx4 %8, %16, off offset:512 sc0 sc1\n\t"
                "global_load_dwordx4 %9, %16, off offset:576 sc0 sc1\n\t"
                "global_load_dwordx4 %10, %16, off offset:640 sc0 sc1\n\t"
                "global_load_dwordx4 %11, %16, off offset:704 sc0 sc1\n\t"
                "global_load_dwordx4 %12, %16, off offset:768 sc0 sc1\n\t"
                "global_load_dwordx4 %13, %16, off offset:832 sc0 sc1\n\t"
                "global_load_dwordx4 %14, %16, off offset:896 sc0 sc1\n\t"
                "global_load_dwordx4 %15, %16, off offset:960 sc0 sc1"
                : "=&v"(hv[0]), "=&v"(hv[1]), "=&v"(hv[2]), "=&v"(hv[3]),
                  "=&v"(hv[4]), "=&v"(hv[5]), "=&v"(hv[6]), "=&v"(hv[7]),
                  "=&v"(hv[8]), "=&v"(hv[9]), "=&v"(hv[10]), "=&v"(hv[11]),
                  "=&v"(hv[12]), "=&v"(hv[13]), "=&v"(hv[14]), "=&v"(hv[15])
                : "v"(hb) : "memory");
        }
        asm volatile("s_waitcnt vmcnt(0)" ::: "memory");   // xg + h arrived
        __builtin_amdgcn_sched_barrier(0);

        if (t > 0) {
            #pragma unroll
            for (int kf = 0; kf < 16; ++kf) {
                short8 a = *(short8*)&hv[kf];
                acc[0] = MFMA(a, wlds[0][kf][lane], acc[0]);
                acc[1] = MFMA(a, wlds[1][kf][lane], acc[1]);
                acc[2] = MFMA(a, wlds[2][kf][lane], acc[2]);
                acc[3] = MFMA(a, wlds[3][kf][lane], acc[3]);
            }
        }

        // ---- gate math (fp32), c in registers; xv unpack: gate g, rows r0..r3 ----
        float hnv[4];
        #pragma unroll
        for (int r = 0; r < 4; ++r) {
            unsigned w0 = (unsigned)xv[0][r >> 1], w1 = (unsigned)xv[1][r >> 1];
            unsigned w2 = (unsigned)xv[2][r >> 1], w3 = (unsigned)xv[3][r >> 1];
            int sh = (r & 1) * 16;
            float iv = acc[0][r] + bf2f((unsigned short)(w0 >> sh));
            float fv2= acc[1][r] + bf2f((unsigned short)(w1 >> sh));
            float gv = acc[2][r] + bf2f((unsigned short)(w2 >> sh));
            float ov = acc[3][r] + bf2f((unsigned short)(w3 >> sh));
            float si = sigmoidf_(iv), sf = sigmoidf_(fv2), so = sigmoidf_(ov);
            float tg = tanhf_(gv);
            float cn = sf * cr[r] + si * tg;
            cr[r] = cn;
            hnv[r] = so * tanhf_(cn);
        }

        // ---- publish h_{t+1}: column-paired u32 agent stores (critical path) ----
        {
            const unsigned pbase = ((unsigned)((t + 1) & 1)) * 16384u + (unsigned)(col >> 1);
            #pragma unroll
            for (int r = 0; r < 4; ++r) {
                unsigned v = f2bf(hnv[r]);
                unsigned p = (unsigned)__shfl_xor((int)v, 1);
                if ((l15 & 1) == 0)
                    __hip_atomic_store(&hbuf[pbase + (unsigned)(mbase + r) * 256], v | (p << 16),
                                       __ATOMIC_RELAXED, __HIP_MEMORY_SCOPE_AGENT);
            }
        }
        // ---- hs history (+ tails), plain cached; folded into the same ack ----
        #pragma unroll
        for (int r = 0; r < 4; ++r) {
            int m = mbase + r;
            hs[((size_t)t * BATCH + m) * HSZ + col] = f2bf(hnv[r]);
        }
        if (t == TLEN - 1) {
            #pragma unroll
            for (int r = 0; r < 4; ++r) {
                int m = mbase + r;
                out_tail[(size_t)m * HSZ + col] = hnv[r];                      // h_T
                out_tail[(size_t)BATCH * HSZ + (size_t)m * HSZ + col] = cr[r]; // c_T
            }
        }
        asm volatile("s_waitcnt vmcnt(0)" ::: "memory");   // publish ack (hs folded in)
        __builtin_amdgcn_sched_barrier(0);
        if (lane == 0)
            __hip_atomic_store(&flags[wave * 32 + wg], t + 1, __ATOMIC_RELAXED, __HIP_MEMORY_SCOPE_AGENT);
    }
}

// ---------------- Phase C: outputs = hs @ W_out^T + b_out (fp32 out) ------------------------
__global__ void __launch_bounds__(512, 1) out_gemm(
    const unsigned short* __restrict__ hs, const float* __restrict__ Wout,
    const float* __restrict__ b_out, float* __restrict__ out)
{
    __shared__ short8 blds[4][16][64];  // 64 KB
    const int tid = threadIdx.x;
    {
        int row = tid >> 3;             // 0..63
        int kseg = (tid & 7) * 64;
        int nt = row >> 4, nn = row & 15;
        const float* src = Wout + (size_t)(blockIdx.y * 64 + row) * HSZ + kseg;
        for (int kk = 0; kk < 64; ++kk) {
            int k = kseg + kk;
            int kf = k >> 5, sub = k & 31;
            ((unsigned short*)&blds[nt][kf][((sub >> 3) << 4) | nn])[sub & 7] = f2bf(src[kk]);
        }
    }
    __syncthreads();
    const int wave = tid >> 6, lane = tid & 63;
    const int m0 = blockIdx.x * 128 + wave * 16;
    f32x4 acc[4];
    #pragma unroll
    for (int i = 0; i < 4; ++i) acc[i] = (f32x4){0.f, 0.f, 0.f, 0.f};
    const unsigned short* arow = hs + (size_t)(m0 + (lane & 15)) * HSZ + ((lane >> 4) * 8);
    #pragma unroll
    for (int kf = 0; kf < 16; ++kf) {
        short8 a = *(const short8*)(arow + kf * 32);
        #pragma unroll
        for (int nt = 0; nt < 4; ++nt)
            acc[nt] = MFMA(a, blds[nt][kf][lane], acc[nt]);
    }
    const int nn = lane & 15;
    #pragma unroll
    for (int nt = 0; nt < 4; ++nt) {
        int nc = blockIdx.y * 64 + nt * 16 + nn;
        float bias = b_out[nc];
        #pragma unroll
        for (int r = 0; r < 4; ++r) {
            int m = m0 + (lane >> 4) * 4 + r;
            out[(size_t)m * OSZ + nc] = acc[nt][r] + bias;
        }
    }
}

extern "C" void kernel_launch(void* const* d_in, const int* in_sizes, int n_in,
                              void* d_out, int out_size, void* d_ws, size_t ws_size,
                              hipStream_t stream)
{
    const float* inputs = (const float*)d_in[0];  // [512,64,256]
    const float* W_ih  = (const float*)d_in[1];   // [2048,256]
    const float* W_hh  = (const float*)d_in[2];   // [2048,512]
    const float* b_ih  = (const float*)d_in[3];
    const float* b_hh  = (const float*)d_in[4];
    const float* W_out = (const float*)d_in[5];   // [256,512]
    const float* b_out = (const float*)d_in[6];
    float* out = (float*)d_out;

    char* ws = (char*)d_ws;
    unsigned short* xg = (unsigned short*)ws;                              // 134,217,728 B
    unsigned short* hs = (unsigned short*)(ws + 134217728);                //  33,554,432 B
    unsigned int* hbuf = (unsigned int*)(ws + 134217728 + 33554432);       //     131,072 B
    int* flags         = (int*)(ws + 134217728 + 33554432 + 131072);       //         512 B

    xg_gemm<<<dim3(256, 16), 512, 0, stream>>>(inputs, W_ih, b_ih, b_hh, xg, flags);

    float* out_tail = out + (size_t)TLEN * BATCH * OSZ;
    const float* whh_p = W_hh;
    const unsigned short* xg_p = xg;
    unsigned short* hs_p = hs;
    unsigned int* hbuf_p = hbuf;
    int* flags_p = flags;
    float* tail_p = out_tail;
    void* scan_args[] = { &whh_p, &xg_p, &hs_p, &hbuf_p, &flags_p, &tail_p };
    hipLaunchCooperativeKernel((void*)lstm_scan, dim3(32), dim3(256), scan_args, 0, stream);

    out_gemm<<<dim3(256, 4), 512, 0, stream>>>(hs, W_out, b_out, out);
}